// Round 6
// baseline (85.615 us; speedup 1.0000x reference)
//
#include <hip/hip_runtime.h>

#define T_STEPS 100
#define BATCH 256
#define NIN 784
#define N0 64
#define N1 64
#define N2 10
#define CHUNK (BATCH*N0 + BATCH*N1 + BATCH*N2)   // 35328
#define NCHUNKS 49                               // 784 / 16
#define NSPLIT 4
#define PLANE (25600*64)                         // one partial plane (floats)
#define BM 256                                   // gemm0 tile rows
#define APAD 260                                 // A row-length pad (floats)

#define FMA4(d, s, v) \
  d.x = fmaf((s), (v).x, d.x); d.y = fmaf((s), (v).y, d.y); \
  d.z = fmaf((s), (v).z, d.z); d.w = fmaf((s), (v).w, d.w);

// ---------------------------------------------------------------------------
// Kernel 1: partial I0 = X @ W0^T. Tile 256x64, 256 threads, micro-tile 8x8
// (0.5 B LDS per FLOP). Double-buffered LDS, one sync per chunk.
// K-split over blockIdx.y, same {13,12,12,12} boundaries as R4 (bit-identical
// association; bias added in reduce_kernel).
// ---------------------------------------------------------------------------
__global__ __launch_bounds__(256) void gemm0_kernel(
    const float* __restrict__ X, const float* __restrict__ W0,
    float* __restrict__ P) {
  __shared__ float As[2][16][APAD];   // [buf][k][row]
  __shared__ float Bs[2][16][68];     // [buf][k][col]

  const int tid = threadIdx.x;
  const int r0  = blockIdx.x * BM;
  const int s   = blockIdx.y;
  const int tn  = tid & 7;            // col-group: cols tn*8..+7
  const int tm  = tid >> 3;           // row-group 0..31: rows tm*8..+7

  const int per  = NCHUNKS / NSPLIT;      // 12
  const int rem  = NCHUNKS % NSPLIT;      // 1
  const int cbeg = s * per + (s < rem ? s : rem);
  const int ccnt = per + (s < rem ? 1 : 0);

  // accumulators: 8 rows x 2 col-quads
  float4 acc[8][2];
#pragma unroll
  for (int i = 0; i < 8; ++i) {
    acc[i][0] = float4{0.f, 0.f, 0.f, 0.f};
    acc[i][1] = float4{0.f, 0.f, 0.f, 0.f};
  }

  // staging maps: thread stages 4 A-rows (f4 each) + 1 B-row (f4)
  const int arow = tid >> 2;          // 0..63 base row
  const int aq   = tid & 3;           // k-quad

  const float* xbase = X  + (size_t)cbeg * 16 + aq * 4;
  const float* wbase = W0 + (size_t)cbeg * 16 + aq * 4;

  // prologue: chunk 0 -> buffer 0
  {
#pragma unroll
    for (int i = 0; i < 4; ++i) {
      int row = arow + i * 64;
      float4 v = *(const float4*)(xbase + (size_t)(r0 + row) * NIN);
      As[0][aq*4+0][row] = v.x;
      As[0][aq*4+1][row] = v.y;
      As[0][aq*4+2][row] = v.z;
      As[0][aq*4+3][row] = v.w;
    }
    {
      int row = arow;                 // 0..63
      float4 v = *(const float4*)(wbase + (size_t)row * NIN);
      Bs[0][aq*4+0][row] = v.x;
      Bs[0][aq*4+1][row] = v.y;
      Bs[0][aq*4+2][row] = v.z;
      Bs[0][aq*4+3][row] = v.w;
    }
  }
  __syncthreads();

  for (int c = 0; c < ccnt; ++c) {
    const int cur = c & 1;
    float4 xa[4], wb;
    const bool more = (c + 1 < ccnt);
    if (more) {                       // issue next-chunk loads BEFORE compute
#pragma unroll
      for (int i = 0; i < 4; ++i) {
        int row = arow + i * 64;
        xa[i] = *(const float4*)(xbase + (size_t)(r0 + row) * NIN + (c + 1) * 16);
      }
      wb = *(const float4*)(wbase + (size_t)arow * NIN + (c + 1) * 16);
    }
#pragma unroll
    for (int k = 0; k < 16; ++k) {
      float4 a0 = *(const float4*)&As[cur][k][tm * 8];
      float4 a1 = *(const float4*)&As[cur][k][tm * 8 + 4];
      float4 b0 = *(const float4*)&Bs[cur][k][tn * 8];
      float4 b1 = *(const float4*)&Bs[cur][k][tn * 8 + 4];
      FMA4(acc[0][0], a0.x, b0); FMA4(acc[0][1], a0.x, b1);
      FMA4(acc[1][0], a0.y, b0); FMA4(acc[1][1], a0.y, b1);
      FMA4(acc[2][0], a0.z, b0); FMA4(acc[2][1], a0.z, b1);
      FMA4(acc[3][0], a0.w, b0); FMA4(acc[3][1], a0.w, b1);
      FMA4(acc[4][0], a1.x, b0); FMA4(acc[4][1], a1.x, b1);
      FMA4(acc[5][0], a1.y, b0); FMA4(acc[5][1], a1.y, b1);
      FMA4(acc[6][0], a1.z, b0); FMA4(acc[6][1], a1.z, b1);
      FMA4(acc[7][0], a1.w, b0); FMA4(acc[7][1], a1.w, b1);
    }
    if (more) {                       // write prefetched chunk to OTHER buffer
      const int nxt = cur ^ 1;
#pragma unroll
      for (int i = 0; i < 4; ++i) {
        int row = arow + i * 64;
        As[nxt][aq*4+0][row] = xa[i].x;
        As[nxt][aq*4+1][row] = xa[i].y;
        As[nxt][aq*4+2][row] = xa[i].z;
        As[nxt][aq*4+3][row] = xa[i].w;
      }
      Bs[nxt][aq*4+0][arow] = wb.x;
      Bs[nxt][aq*4+1][arow] = wb.y;
      Bs[nxt][aq*4+2][arow] = wb.z;
      Bs[nxt][aq*4+3][arow] = wb.w;
    }
    __syncthreads();
  }

  float* op = P + (size_t)s * PLANE;
#pragma unroll
  for (int i = 0; i < 8; ++i) {
    const int row = r0 + tm * 8 + i;
    *(float4*)(op + (size_t)row * N0 + tn * 8)     = acc[i][0];
    *(float4*)(op + (size_t)row * N0 + tn * 8 + 4) = acc[i][1];
  }
}

// ---------------------------------------------------------------------------
// Kernel 2: I0T[b][t][j] = sum_s P[s][t*256+b][j] + b0[j]   (b-major output)
// ---------------------------------------------------------------------------
__global__ __launch_bounds__(256) void reduce_kernel(
    const float* __restrict__ P, const float* __restrict__ b0,
    float* __restrict__ I0T) {
  const int f   = blockIdx.x * 256 + threadIdx.x;  // f4 index 0..409599
  const int j4  = f & 15;
  const int row = f >> 4;          // t*256 + b
  const int t   = row >> 8;
  const int b   = row & 255;

  const float4* p = (const float4*)P;
  float4 v  = p[f];
  float4 u1 = p[(size_t)(PLANE/4) * 1 + f];
  float4 u2 = p[(size_t)(PLANE/4) * 2 + f];
  float4 u3 = p[(size_t)(PLANE/4) * 3 + f];
  v.x += u1.x; v.y += u1.y; v.z += u1.z; v.w += u1.w;
  v.x += u2.x; v.y += u2.y; v.z += u2.z; v.w += u2.w;
  v.x += u3.x; v.y += u3.y; v.z += u3.z; v.w += u3.w;
  float4 bv = ((const float4*)b0)[j4];
  v.x += bv.x; v.y += bv.y; v.z += bv.z; v.w += bv.w;

  ((float4*)I0T)[((size_t)b * T_STEPS + t) * 16 + j4] = v;
}

// ---------------------------------------------------------------------------
// Kernel 3: one block per batch element (unchanged from R5).
// ---------------------------------------------------------------------------
__global__ __launch_bounds__(256) void fused_kernel(
    const float* __restrict__ I0T,
    const float* __restrict__ W1, const float* __restrict__ b1,
    const float* __restrict__ W2, const float* __restrict__ b2,
    float* __restrict__ out) {
  __shared__ float bufA[112][68];       // I0 -> z0 -> I1 -> z1 (in place)
  __shared__ float sW1t[64][68];        // W1 transposed [j][i]
  __shared__ float sW2[N2][68];
  __shared__ float sI2[T_STEPS][N2];

  const int b   = blockIdx.x;
  const int tid = threadIdx.x;
  const int j   = tid & 63;
  const int tq  = tid >> 6;
  float* outSpk = out;                        // [T][B][10]
  float* laySpk = out + T_STEPS * BATCH * N2; // [T][35328]

  // ---- stage I0 slab (contiguous per block)
  {
    const float4* src = (const float4*)I0T + (size_t)b * (T_STEPS * 16);
    for (int idx = tid; idx < T_STEPS * 16; idx += 256) {
      float4 v = src[idx];
      int t = idx >> 4, j4 = idx & 15;
      *(float4*)&bufA[t][j4 * 4] = v;
    }
  }
  __syncthreads();

  // ---- scan0 (wave 0, batched) || W1/W2 staging (waves 1-3)
  if (tq == 0) {
    float v = 0.0f;
#pragma unroll
    for (int g = 0; g < 4; ++g) {
      float ic[25];
#pragma unroll
      for (int i = 0; i < 25; ++i) ic[i] = bufA[g * 25 + i][j];
#pragma unroll
      for (int i = 0; i < 25; ++i) {
        v = v + 0.05f * ((0.0f - v) + ic[i]);
        float z = (v > 1.0f) ? 1.0f : 0.0f;
        v -= z;
        ic[i] = z;
      }
#pragma unroll
      for (int i = 0; i < 25; ++i) bufA[g * 25 + i][j] = ic[i];
    }
  } else {
    for (int idx = tid - 64; idx < 64 * 16; idx += 192) {
      int i = idx >> 4, jv = idx & 15;
      float4 w = *(const float4*)(W1 + (size_t)i * 64 + jv * 4);
      sW1t[jv * 4 + 0][i] = w.x;
      sW1t[jv * 4 + 1][i] = w.y;
      sW1t[jv * 4 + 2][i] = w.z;
      sW1t[jv * 4 + 3][i] = w.w;
    }
    for (int idx = tid - 64; idx < N2 * 16; idx += 192) {
      int o = idx >> 4, jv = idx & 15;
      *(float4*)&sW2[o][jv * 4] = *(const float4*)(W2 + (size_t)o * 64 + jv * 4);
    }
  }
  __syncthreads();

  // ---- z0 -> layer_spikes
  for (int idx = tid; idx < T_STEPS * 16; idx += 256) {
    int t = idx >> 4, jv = idx & 15;
    *(float4*)(laySpk + (size_t)t * CHUNK + b * 64 + jv * 4) =
        *(const float4*)&bufA[t][jv * 4];
  }

  // ---- GEMM1: I1[t][i] = b1[i] + sum_j z0[t][j]*W1[i][j]
  const int iq = tid & 15;
  const int ts = tid >> 4;
  float g1[4][7];
  {
    float4 bias = *(const float4*)(b1 + iq * 4);
#pragma unroll
    for (int tt = 0; tt < 7; ++tt) {
      g1[0][tt] = bias.x; g1[1][tt] = bias.y; g1[2][tt] = bias.z; g1[3][tt] = bias.w;
    }
#pragma unroll
    for (int jq = 0; jq < 16; ++jq) {
      float4 z4[7];
#pragma unroll
      for (int tt = 0; tt < 7; ++tt)
        z4[tt] = *(const float4*)&bufA[ts * 7 + tt][jq * 4];
      float4 w4[4];
#pragma unroll
      for (int e = 0; e < 4; ++e)
        w4[e] = *(const float4*)&sW1t[jq * 4 + e][iq * 4];
#pragma unroll
      for (int e = 0; e < 4; ++e) {
#pragma unroll
        for (int tt = 0; tt < 7; ++tt) {
          float zv = ((const float*)&z4[tt])[e];
          g1[0][tt] = fmaf(zv, w4[e].x, g1[0][tt]);
          g1[1][tt] = fmaf(zv, w4[e].y, g1[1][tt]);
          g1[2][tt] = fmaf(zv, w4[e].z, g1[2][tt]);
          g1[3][tt] = fmaf(zv, w4[e].w, g1[3][tt]);
        }
      }
    }
  }
  __syncthreads();            // all z0 reads complete
#pragma unroll
  for (int tt = 0; tt < 7; ++tt) {
    float4 o = {g1[0][tt], g1[1][tt], g1[2][tt], g1[3][tt]};
    *(float4*)&bufA[ts * 7 + tt][iq * 4] = o;
  }
  __syncthreads();

  // ---- scan1 (wave 0, batched)
  if (tq == 0) {
    float v = 0.0f;
#pragma unroll
    for (int g = 0; g < 4; ++g) {
      float ic[25];
#pragma unroll
      for (int i = 0; i < 25; ++i) ic[i] = bufA[g * 25 + i][j];
#pragma unroll
      for (int i = 0; i < 25; ++i) {
        v = v + 0.05f * ((0.0f - v) + ic[i]);
        float z = (v > 1.0f) ? 1.0f : 0.0f;
        v -= z;
        ic[i] = z;
      }
#pragma unroll
      for (int i = 0; i < 25; ++i) bufA[g * 25 + i][j] = ic[i];
    }
  }
  __syncthreads();

  // ---- z1 -> layer_spikes
  for (int idx = tid; idx < T_STEPS * 16; idx += 256) {
    int t = idx >> 4, jv = idx & 15;
    *(float4*)(laySpk + (size_t)t * CHUNK + BATCH * N0 + b * 64 + jv * 4) =
        *(const float4*)&bufA[t][jv * 4];
  }

  // ---- GEMM2: I2[t][o] = b2[o] + sum_j z1[t][j]*W2[o][j]
  for (int idx = tid; idx < T_STEPS * N2; idx += 256) {
    int t = idx / N2, o = idx % N2;
    float a = b2[o];
#pragma unroll
    for (int jq = 0; jq < 16; ++jq) {
      float4 z = *(const float4*)&bufA[t][jq * 4];
      float4 w = *(const float4*)&sW2[o][jq * 4];
      a += z.x * w.x;
      a += z.y * w.y;
      a += z.z * w.z;
      a += z.w * w.w;
    }
    sI2[t][o] = a;
  }
  __syncthreads();

  // ---- scan2 (10 chains, batched)
  if (tid < N2) {
    float v = 0.0f;
#pragma unroll
    for (int g = 0; g < 4; ++g) {
      float ic[25];
#pragma unroll
      for (int i = 0; i < 25; ++i) ic[i] = sI2[g * 25 + i][tid];
#pragma unroll
      for (int i = 0; i < 25; ++i) {
        v = v + 0.05f * ((0.0f - v) + ic[i]);
        float z = (v > 1.0f) ? 1.0f : 0.0f;
        v -= z;
        ic[i] = z;
      }
#pragma unroll
      for (int i = 0; i < 25; ++i) sI2[g * 25 + i][tid] = ic[i];
    }
  }
  __syncthreads();

  // ---- z2 -> out_spikes + layer_spikes
  for (int idx = tid; idx < T_STEPS * N2; idx += 256) {
    int t = idx / N2, o = idx % N2;
    float z = sI2[t][o];
    outSpk[(size_t)t * (BATCH * N2) + b * N2 + o] = z;
    laySpk[(size_t)t * CHUNK + BATCH * (N0 + N1) + b * N2 + o] = z;
  }
}

extern "C" void kernel_launch(void* const* d_in, const int* in_sizes, int n_in,
                              void* d_out, int out_size, void* d_ws, size_t ws_size,
                              hipStream_t stream) {
  const float* inp = (const float*)d_in[0];
  const float* W0  = (const float*)d_in[1];
  const float* b0  = (const float*)d_in[2];
  const float* W1  = (const float*)d_in[3];
  const float* b1  = (const float*)d_in[4];
  const float* W2  = (const float*)d_in[5];
  const float* b2  = (const float*)d_in[6];

  float* P   = (float*)d_ws;                       // 4 planes, 26.2 MB
  float* I0T = P + (size_t)NSPLIT * PLANE;         // 6.55 MB, b-major

  gemm0_kernel<<<dim3(25600 / BM, NSPLIT), dim3(256), 0, stream>>>(inp, W0, P);
  reduce_kernel<<<dim3(1600), dim3(256), 0, stream>>>(P, b0, I0T);
  fused_kernel<<<dim3(BATCH), dim3(256), 0, stream>>>(I0T, W1, b1, W2, b2,
                                                      (float*)d_out);
}

// Round 7
// 68.253 us; speedup vs baseline: 1.2544x; 1.2544x over previous
//
#include <hip/hip_runtime.h>

#define T_STEPS 100
#define BATCH 256
#define NIN 784
#define N0 64
#define N1 64
#define N2 10
#define CHUNK (BATCH*N0 + BATCH*N1 + BATCH*N2)   // 35328
#define NCHUNKS 49                               // 784 / 16
#define NSPLIT 4
#define PLANE (BATCH*T_STEPS*64)                 // one partial plane (floats), b-major [b][t][j]
#define BM 128                                   // gemm0 tile rows

#define FMA4(d, s, v) \
  d.x = fmaf((s), (v).x, d.x); d.y = fmaf((s), (v).y, d.y); \
  d.z = fmaf((s), (v).z, d.z); d.w = fmaf((s), (v).w, d.w);

// ---------------------------------------------------------------------------
// Kernel 1: partial I0 = X @ W0^T. Tile 128x64, 256 threads, micro-tile 8x4
// (0.75 B LDS per FLOP; acc=32 VGPR). Double-buffered LDS, one sync/chunk.
// K-split over blockIdx.y, {13,12,12,12} chunk boundaries (FP order identical
// to R4). Output written b-major: P[s][b][t][j] (tile lies in a single t).
// ---------------------------------------------------------------------------
__global__ __launch_bounds__(256) void gemm0_kernel(
    const float* __restrict__ X, const float* __restrict__ W0,
    float* __restrict__ P) {
  __shared__ float As[2][16][132];   // [buf][k][row]
  __shared__ float Bs[2][16][68];    // [buf][k][col]

  const int tid = threadIdx.x;
  const int r0  = blockIdx.x * BM;
  const int s   = blockIdx.y;
  const int tn  = tid & 15;          // col-group: cols tn*4..+3
  const int tm  = tid >> 4;          // row-group 0..15: rows tm*8..+7

  const int per  = NCHUNKS / NSPLIT;      // 12
  const int rem  = NCHUNKS % NSPLIT;      // 1
  const int cbeg = s * per + (s < rem ? s : rem);
  const int ccnt = per + (s < rem ? 1 : 0);

  float4 acc[8];                     // acc[i] = cols tn*4..+3 of row tm*8+i
#pragma unroll
  for (int i = 0; i < 8; ++i) acc[i] = float4{0.f, 0.f, 0.f, 0.f};

  // staging: A = 512 f4 (2/thread), B = 256 f4 (1/thread)
  const int arow = tid >> 2;         // 0..63
  const int aq   = tid & 3;          // k-quad

  const float* xbase = X  + (size_t)cbeg * 16 + aq * 4;
  const float* wbase = W0 + (size_t)cbeg * 16 + aq * 4;

  // prologue: chunk 0 -> buffer 0
  {
#pragma unroll
    for (int i = 0; i < 2; ++i) {
      int row = arow + i * 64;
      float4 v = *(const float4*)(xbase + (size_t)(r0 + row) * NIN);
      As[0][aq*4+0][row] = v.x;
      As[0][aq*4+1][row] = v.y;
      As[0][aq*4+2][row] = v.z;
      As[0][aq*4+3][row] = v.w;
    }
    {
      float4 v = *(const float4*)(wbase + (size_t)arow * NIN);
      Bs[0][aq*4+0][arow] = v.x;
      Bs[0][aq*4+1][arow] = v.y;
      Bs[0][aq*4+2][arow] = v.z;
      Bs[0][aq*4+3][arow] = v.w;
    }
  }
  __syncthreads();

  for (int c = 0; c < ccnt; ++c) {
    const int cur = c & 1;
    float4 xa[2], wb;
    const bool more = (c + 1 < ccnt);
    if (more) {                      // issue next-chunk loads BEFORE compute
#pragma unroll
      for (int i = 0; i < 2; ++i) {
        int row = arow + i * 64;
        xa[i] = *(const float4*)(xbase + (size_t)(r0 + row) * NIN + (c + 1) * 16);
      }
      wb = *(const float4*)(wbase + (size_t)arow * NIN + (c + 1) * 16);
    }
#pragma unroll 4
    for (int k = 0; k < 16; ++k) {
      float4 a0 = *(const float4*)&As[cur][k][tm * 8];
      float4 a1 = *(const float4*)&As[cur][k][tm * 8 + 4];
      float4 b  = *(const float4*)&Bs[cur][k][tn * 4];
      FMA4(acc[0], a0.x, b);
      FMA4(acc[1], a0.y, b);
      FMA4(acc[2], a0.z, b);
      FMA4(acc[3], a0.w, b);
      FMA4(acc[4], a1.x, b);
      FMA4(acc[5], a1.y, b);
      FMA4(acc[6], a1.z, b);
      FMA4(acc[7], a1.w, b);
    }
    if (more) {                      // write prefetched chunk to OTHER buffer
      const int nxt = cur ^ 1;
#pragma unroll
      for (int i = 0; i < 2; ++i) {
        int row = arow + i * 64;
        As[nxt][aq*4+0][row] = xa[i].x;
        As[nxt][aq*4+1][row] = xa[i].y;
        As[nxt][aq*4+2][row] = xa[i].z;
        As[nxt][aq*4+3][row] = xa[i].w;
      }
      Bs[nxt][aq*4+0][arow] = wb.x;
      Bs[nxt][aq*4+1][arow] = wb.y;
      Bs[nxt][aq*4+2][arow] = wb.z;
      Bs[nxt][aq*4+3][arow] = wb.w;
    }
    __syncthreads();
  }

  // epilogue: b-major write. Whole tile has one t (BM=128 divides 256-row t).
  const int t0  = r0 >> 8;
  const int bb0 = r0 & 255;
  float* op = P + (size_t)s * PLANE;
#pragma unroll
  for (int i = 0; i < 8; ++i) {
    const int bb = bb0 + tm * 8 + i;
    *(float4*)(op + ((size_t)bb * T_STEPS + t0) * 64 + tn * 4) = acc[i];
  }
}

// ---------------------------------------------------------------------------
// Kernel 2: one block per batch element. Staging sums the 4 b-major plane
// slabs (contiguous 25.6 KB each) + bias, exact R4-reduce add order.
// Then scan0 -> GEMM1 -> scan1 -> GEMM2 -> scan2, all LDS-resident.
// ---------------------------------------------------------------------------
__global__ __launch_bounds__(256) void fused_kernel(
    const float* __restrict__ P, const float* __restrict__ b0,
    const float* __restrict__ W1, const float* __restrict__ b1,
    const float* __restrict__ W2, const float* __restrict__ b2,
    float* __restrict__ out) {
  __shared__ float bufA[112][68];       // I0 -> z0 -> I1 -> z1 (in place)
  __shared__ float sW1t[64][68];        // W1 transposed [j][i]
  __shared__ float sW2[N2][68];
  __shared__ float sI2[T_STEPS][N2];

  const int b   = blockIdx.x;
  const int tid = threadIdx.x;
  const int j   = tid & 63;
  const int tq  = tid >> 6;
  float* outSpk = out;                        // [T][B][10]
  float* laySpk = out + T_STEPS * BATCH * N2; // [T][35328]

  // ---- stage I0 = sum_s P[s][b] + b0  (each slab contiguous)
  {
    const float4* base = (const float4*)P + (size_t)b * (T_STEPS * 16);
    const size_t pstep = PLANE / 4;
    for (int idx = tid; idx < T_STEPS * 16; idx += 256) {
      float4 v  = base[idx];
      float4 u1 = base[idx + pstep];
      float4 u2 = base[idx + 2 * pstep];
      float4 u3 = base[idx + 3 * pstep];
      v.x += u1.x; v.y += u1.y; v.z += u1.z; v.w += u1.w;
      v.x += u2.x; v.y += u2.y; v.z += u2.z; v.w += u2.w;
      v.x += u3.x; v.y += u3.y; v.z += u3.z; v.w += u3.w;
      int t = idx >> 4, j4 = idx & 15;
      float4 bv = ((const float4*)b0)[j4];
      v.x += bv.x; v.y += bv.y; v.z += bv.z; v.w += bv.w;
      *(float4*)&bufA[t][j4 * 4] = v;
    }
  }
  __syncthreads();

  // ---- scan0 (wave 0, batched) || W1/W2 staging (waves 1-3)
  if (tq == 0) {
    float v = 0.0f;
#pragma unroll
    for (int g = 0; g < 4; ++g) {
      float ic[25];
#pragma unroll
      for (int i = 0; i < 25; ++i) ic[i] = bufA[g * 25 + i][j];
#pragma unroll
      for (int i = 0; i < 25; ++i) {
        v = v + 0.05f * ((0.0f - v) + ic[i]);
        float z = (v > 1.0f) ? 1.0f : 0.0f;
        v -= z;
        ic[i] = z;
      }
#pragma unroll
      for (int i = 0; i < 25; ++i) bufA[g * 25 + i][j] = ic[i];
    }
  } else {
    for (int idx = tid - 64; idx < 64 * 16; idx += 192) {
      int i = idx >> 4, jv = idx & 15;
      float4 w = *(const float4*)(W1 + (size_t)i * 64 + jv * 4);
      sW1t[jv * 4 + 0][i] = w.x;
      sW1t[jv * 4 + 1][i] = w.y;
      sW1t[jv * 4 + 2][i] = w.z;
      sW1t[jv * 4 + 3][i] = w.w;
    }
    for (int idx = tid - 64; idx < N2 * 16; idx += 192) {
      int o = idx >> 4, jv = idx & 15;
      *(float4*)&sW2[o][jv * 4] = *(const float4*)(W2 + (size_t)o * 64 + jv * 4);
    }
  }
  __syncthreads();

  // ---- z0 -> layer_spikes
  for (int idx = tid; idx < T_STEPS * 16; idx += 256) {
    int t = idx >> 4, jv = idx & 15;
    *(float4*)(laySpk + (size_t)t * CHUNK + b * 64 + jv * 4) =
        *(const float4*)&bufA[t][jv * 4];
  }

  // ---- GEMM1: I1[t][i] = b1[i] + sum_j z0[t][j]*W1[i][j]
  const int iq = tid & 15;
  const int ts = tid >> 4;
  float g1[4][7];
  {
    float4 bias = *(const float4*)(b1 + iq * 4);
#pragma unroll
    for (int tt = 0; tt < 7; ++tt) {
      g1[0][tt] = bias.x; g1[1][tt] = bias.y; g1[2][tt] = bias.z; g1[3][tt] = bias.w;
    }
#pragma unroll
    for (int jq = 0; jq < 16; ++jq) {
      float4 z4[7];
#pragma unroll
      for (int tt = 0; tt < 7; ++tt)
        z4[tt] = *(const float4*)&bufA[ts * 7 + tt][jq * 4];
      float4 w4[4];
#pragma unroll
      for (int e = 0; e < 4; ++e)
        w4[e] = *(const float4*)&sW1t[jq * 4 + e][iq * 4];
#pragma unroll
      for (int e = 0; e < 4; ++e) {
#pragma unroll
        for (int tt = 0; tt < 7; ++tt) {
          float zv = ((const float*)&z4[tt])[e];
          g1[0][tt] = fmaf(zv, w4[e].x, g1[0][tt]);
          g1[1][tt] = fmaf(zv, w4[e].y, g1[1][tt]);
          g1[2][tt] = fmaf(zv, w4[e].z, g1[2][tt]);
          g1[3][tt] = fmaf(zv, w4[e].w, g1[3][tt]);
        }
      }
    }
  }
  __syncthreads();            // all z0 reads complete
#pragma unroll
  for (int tt = 0; tt < 7; ++tt) {
    float4 o = {g1[0][tt], g1[1][tt], g1[2][tt], g1[3][tt]};
    *(float4*)&bufA[ts * 7 + tt][iq * 4] = o;
  }
  __syncthreads();

  // ---- scan1 (wave 0, batched)
  if (tq == 0) {
    float v = 0.0f;
#pragma unroll
    for (int g = 0; g < 4; ++g) {
      float ic[25];
#pragma unroll
      for (int i = 0; i < 25; ++i) ic[i] = bufA[g * 25 + i][j];
#pragma unroll
      for (int i = 0; i < 25; ++i) {
        v = v + 0.05f * ((0.0f - v) + ic[i]);
        float z = (v > 1.0f) ? 1.0f : 0.0f;
        v -= z;
        ic[i] = z;
      }
#pragma unroll
      for (int i = 0; i < 25; ++i) bufA[g * 25 + i][j] = ic[i];
    }
  }
  __syncthreads();

  // ---- z1 -> layer_spikes
  for (int idx = tid; idx < T_STEPS * 16; idx += 256) {
    int t = idx >> 4, jv = idx & 15;
    *(float4*)(laySpk + (size_t)t * CHUNK + BATCH * N0 + b * 64 + jv * 4) =
        *(const float4*)&bufA[t][jv * 4];
  }

  // ---- GEMM2: I2[t][o] = b2[o] + sum_j z1[t][j]*W2[o][j]
  for (int idx = tid; idx < T_STEPS * N2; idx += 256) {
    int t = idx / N2, o = idx % N2;
    float a = b2[o];
#pragma unroll
    for (int jq = 0; jq < 16; ++jq) {
      float4 z = *(const float4*)&bufA[t][jq * 4];
      float4 w = *(const float4*)&sW2[o][jq * 4];
      a += z.x * w.x;
      a += z.y * w.y;
      a += z.z * w.z;
      a += z.w * w.w;
    }
    sI2[t][o] = a;
  }
  __syncthreads();

  // ---- scan2 (10 chains, batched)
  if (tid < N2) {
    float v = 0.0f;
#pragma unroll
    for (int g = 0; g < 4; ++g) {
      float ic[25];
#pragma unroll
      for (int i = 0; i < 25; ++i) ic[i] = sI2[g * 25 + i][tid];
#pragma unroll
      for (int i = 0; i < 25; ++i) {
        v = v + 0.05f * ((0.0f - v) + ic[i]);
        float z = (v > 1.0f) ? 1.0f : 0.0f;
        v -= z;
        ic[i] = z;
      }
#pragma unroll
      for (int i = 0; i < 25; ++i) sI2[g * 25 + i][tid] = ic[i];
    }
  }
  __syncthreads();

  // ---- z2 -> out_spikes + layer_spikes
  for (int idx = tid; idx < T_STEPS * N2; idx += 256) {
    int t = idx / N2, o = idx % N2;
    float z = sI2[t][o];
    outSpk[(size_t)t * (BATCH * N2) + b * N2 + o] = z;
    laySpk[(size_t)t * CHUNK + BATCH * (N0 + N1) + b * N2 + o] = z;
  }
}

extern "C" void kernel_launch(void* const* d_in, const int* in_sizes, int n_in,
                              void* d_out, int out_size, void* d_ws, size_t ws_size,
                              hipStream_t stream) {
  const float* inp = (const float*)d_in[0];
  const float* W0  = (const float*)d_in[1];
  const float* b0  = (const float*)d_in[2];
  const float* W1  = (const float*)d_in[3];
  const float* b1  = (const float*)d_in[4];
  const float* W2  = (const float*)d_in[5];
  const float* b2  = (const float*)d_in[6];

  float* P = (float*)d_ws;   // 4 planes x 6.55 MB, b-major [s][b][t][j]

  gemm0_kernel<<<dim3(25600 / BM, NSPLIT), dim3(256), 0, stream>>>(inp, W0, P);
  fused_kernel<<<dim3(BATCH), dim3(256), 0, stream>>>(P, b0, W1, b1, W2, b2,
                                                      (float*)d_out);
}